// Round 13
// baseline (320.063 us; speedup 1.0000x reference)
//
#include <hip/hip_runtime.h>
#include <hip/hip_fp16.h>

// GAT (3-layer) on MI355X. N=50000 nodes, E=800000 edges, D=64, H=2/2/1.
// R19: layer-(l+1) GEMM fused into layer-l agg. An agg block ends holding a
//      16-node x 128-col h tile = one MFMA M=16 tile: h -> LDS f16 (4.4KB,
//      +8 pad), barrier, 8x mfma_f32_16x16x32_f16 per wave (wave = 32 cols =
//      half a head; B-frags read DIRECT from L2-hot Wt, no staging), fused
//      el/er butterfly (2 waves/head combined via LDS atomicAdd), write
//      fhb_next + elr_next. Deletes both standalone IN=128 GEMMs, the bf16 hb
//      buffer (25.6MB traffic), 2 launches. Weights bf16->f16 everywhere
//      (same bytes, more mantissa). fhb/elr ping-pong (FA/FB, EA/EB) avoids
//      gather-vs-write races. R18 kept: gemm0||hist fusion, 4-deep agg.

typedef __attribute__((ext_vector_type(8))) _Float16 half8;  // 8 f16 (4 VGPRs)
typedef __attribute__((ext_vector_type(4))) float float4v;   // 4 fp32 acc

__device__ __forceinline__ float lrelu(float x){ return fmaxf(x, 0.2f*x); }

__device__ __forceinline__ unsigned short f2h(float f){
  return __half_as_ushort(__float2half(f));
}
__device__ __forceinline__ float elu1(float x){            // elu, x<0 branch via exp
  return x > 0.f ? x : (__expf(x) - 1.f);
}

__global__ void k_scan_local(const int* __restrict__ counts, int* __restrict__ row_ptr,
                             int* __restrict__ bsum, int N){
  __shared__ int s[256];
  int t = threadIdx.x, g = blockIdx.x*256 + t;
  int v = (g < N) ? counts[g] : 0;
  s[t] = v; __syncthreads();
  #pragma unroll
  for (int off = 1; off < 256; off <<= 1){
    int x = 0;
    if (t >= off) x = s[t-off];
    __syncthreads();
    s[t] += x;
    __syncthreads();
  }
  if (g < N) row_ptr[g+1] = s[t];
  if (g == 0 && t == 0) row_ptr[0] = 0;
  if (t == 255) bsum[blockIdx.x] = s[255];
}

__global__ void k_scan_top(int* __restrict__ bsum, int nb){
  __shared__ int s[256];
  int t = threadIdx.x;
  int v = (t < nb) ? bsum[t] : 0;
  s[t] = v; __syncthreads();
  #pragma unroll
  for (int off = 1; off < 256; off <<= 1){
    int x = 0;
    if (t >= off) x = s[t-off];
    __syncthreads();
    s[t] += x;
    __syncthreads();
  }
  if (t < nb) bsum[t] = s[t] - v;  // exclusive block offsets
}

__global__ void k_scan_fix(int* __restrict__ row_ptr, const int* __restrict__ bsum, int N){
  int g = blockIdx.x*256 + threadIdx.x;
  if (g < N && blockIdx.x > 0) row_ptr[g+1] += bsum[blockIdx.x];
}

// atomic-free scatter: pos comes from rank captured during hist
__global__ void k_scatter2(const int* __restrict__ src, const int* __restrict__ dst,
                           const int* __restrict__ rank, const int* __restrict__ row_ptr,
                           int* __restrict__ ssrc, int E){
  int i = blockIdx.x*blockDim.x + threadIdx.x;
  if (i < E) ssrc[row_ptr[dst[i]] + rank[i]] = src[i];
}

// Fused setup: zero counts + all three weight preps (f16 now).
// Wt layout: [n][IN] f16 (n-major). W0: 64x128; W1: 128x128; W2|rW2: 128x(64+64).
__global__ void k_setup(int* __restrict__ counts, int N,
                        const float* __restrict__ W0, const float* __restrict__ W1,
                        const float* __restrict__ W2, const float* __restrict__ rW2,
                        unsigned short* __restrict__ Wt0, unsigned short* __restrict__ Wt1,
                        unsigned short* __restrict__ Wt2){
  int id = blockIdx.x*256 + threadIdx.x;
  if (id < N){ counts[id] = 0; return; }
  int j = id - N;
  if (j < 128*64){
    int n = j/64, k = j%64;
    Wt0[n*64 + k] = f2h(W0[k*128 + n]);
  } else if (j < 128*64 + 128*128){
    int i = j - 128*64; int n = i/128, k = i%128;
    Wt1[n*128 + k] = f2h(W1[k*128 + n]);
  } else if (j < 128*64 + 2*128*128){
    int i = j - 128*64 - 128*128; int n = i/128, k = i%128;
    float v = (n < 64) ? W2[k*64 + n] : rW2[k*64 + (n - 64)];
    Wt2[n*128 + k] = f2h(v);
  }
}

// Fused layer-0 GEMM (EMBED, IN=64, f16 MFMA) + edge histogram: blocks [0,gt)
// run the gemm; blocks [gt, gt+eb) run hist_rank (~40us fabric-atomic floor,
// hidden under the gemm). fhb[N][128] f16 + elr out.
__global__ __launch_bounds__(256) void k_gemm0_hist(
    const int* __restrict__ feat, const float* __restrict__ fv,
    const float* __restrict__ embp,
    const unsigned short* __restrict__ Wt,   // [128][64] f16 n-major
    const float* __restrict__ al, const float* __restrict__ ar,
    unsigned short* __restrict__ fhb, float* __restrict__ elr, int N, int gt,
    const int* __restrict__ dst, int* __restrict__ counts,
    int* __restrict__ rank, int E){
  constexpr int IN = 64, KS = IN/32, LDP = IN + 8;
  __shared__ unsigned short Wt_s[128*LDP];
  if ((int)blockIdx.x >= gt){
    int i = ((int)blockIdx.x - gt)*256 + threadIdx.x;
    if (i < E){
      int d = dst[i];
      rank[i] = atomicAdd(&counts[d], 1);
    }
    return;
  }
  const int t = threadIdx.x;
  const int lane = t & 63, wid = t >> 6;
  const int l15 = lane & 15, quad = lane >> 4;
  const int row0 = blockIdx.x*64 + wid*16;

  // stage Wt -> LDS (uint4 = 8 f16)
  for (int id = t; id < 128*(IN/8); id += 256){
    int r = id/(IN/8), seg = id%(IN/8);
    ((uint4*)(Wt_s + r*LDP))[seg] = ((const uint4*)(Wt + (size_t)r*IN))[seg];
  }
  // A fragments: emb[feat[n]]*fv[n] -> f16 (overlaps LDS staging)
  half8 a[KS];
  int arow = row0 + l15;
  if (arow < N){
    const float* er2 = embp + (size_t)feat[arow]*64;
    float sc = fv[arow];
    #pragma unroll
    for (int s = 0; s < KS; s++){
      const float4* p = (const float4*)(er2 + s*32 + quad*8);
      float4 v0 = p[0], v1 = p[1];
      half8 ta;
      ta[0] = (_Float16)(v0.x*sc); ta[1] = (_Float16)(v0.y*sc);
      ta[2] = (_Float16)(v0.z*sc); ta[3] = (_Float16)(v0.w*sc);
      ta[4] = (_Float16)(v1.x*sc); ta[5] = (_Float16)(v1.y*sc);
      ta[6] = (_Float16)(v1.z*sc); ta[7] = (_Float16)(v1.w*sc);
      a[s] = ta;
    }
  } else {
    #pragma unroll
    for (int s = 0; s < KS; s++) a[s] = half8{0,0,0,0,0,0,0,0};
  }
  __syncthreads();

  float4v acc[8];
  #pragma unroll
  for (int nt = 0; nt < 8; nt++) acc[nt] = float4v{0.f,0.f,0.f,0.f};
  #pragma unroll
  for (int nt = 0; nt < 8; nt++){
    #pragma unroll
    for (int s = 0; s < KS; s++){
      half8 b = *(const half8*)(Wt_s + (nt*16 + l15)*LDP + s*32 + quad*8);
      acc[nt] = __builtin_amdgcn_mfma_f32_16x16x32_f16(a[s], b, acc[nt], 0, 0, 0);
    }
  }

  float alc[8], arc[8];
  #pragma unroll
  for (int nt = 0; nt < 8; nt++){
    alc[nt] = al[nt*16 + l15];
    arc[nt] = ar[nt*16 + l15];
  }
  #pragma unroll
  for (int reg = 0; reg < 4; reg++){
    int row = row0 + quad*4 + reg;
    bool rv = row < N;
    if (rv){
      #pragma unroll
      for (int nt = 0; nt < 8; nt++)
        fhb[(size_t)row*128 + nt*16 + l15] = f2h(acc[nt][reg]);
    }
    float pel0 = 0.f, per0 = 0.f, pel1 = 0.f, per1 = 0.f;
    #pragma unroll
    for (int nt = 0; nt < 4; nt++){
      pel0 += acc[nt][reg]*alc[nt];     per0 += acc[nt][reg]*arc[nt];
      pel1 += acc[nt+4][reg]*alc[nt+4]; per1 += acc[nt+4][reg]*arc[nt+4];
    }
    #pragma unroll
    for (int off = 1; off < 16; off <<= 1){   // reduce across the quad's 16 lanes
      pel0 += __shfl_xor(pel0, off, 64);
      pel1 += __shfl_xor(pel1, off, 64);
      per0 += __shfl_xor(per0, off, 64);
      per1 += __shfl_xor(per1, off, 64);
    }
    if (l15 == 0 && rv){
      elr[row*4+0] = pel0;
      elr[row*4+1] = pel1;
      elr[row*4+2] = per0;
      elr[row*4+3] = per1;
    }
  }
}

// FUSED agg(H=2) + next-layer GEMM. Block = 16 nodes (16 groups x 16 lanes).
// Agg phase = R15's group-per-node 4-deep gather; epilogue packs h (post-elu)
// to an LDS f16 tile [16][136] (+8 pad -> 2-way banks). GEMM phase: wave wid
// owns cols wid*32..wid*32+31 (one half of head wid>>1): A-frags from LDS,
// B-frags DIRECT from global Wt (L2-hot 32KB), 8 MFMAs; el/er per-wave
// butterfly + LDS atomicAdd combine (2 waves/head); write fhb_out + elr_out.
// HN==1: cols>=64 get al/ar=0 (elr heads 1 stay 0).
template<int HN>
__global__ __launch_bounds__(256) void k_agg_gemm(
    const unsigned short* __restrict__ fhb,  // [N][128] f16 (layer input fh)
    const float* __restrict__ elr,           // [N][4]
    const int* __restrict__ row_ptr, const int* __restrict__ ssrc,
    const float* __restrict__ bias, const float* __restrict__ res,
    float* __restrict__ out,                 // f32 [N][128] residual out, or null
    const unsigned short* __restrict__ Wtn,  // [128][128] f16 n-major
    const float* __restrict__ aln, const float* __restrict__ arn,
    unsigned short* __restrict__ fhb_out, float* __restrict__ elr_out, int N){
  __shared__ _Float16 h_s[16*136];           // +8 pad: 272B row stride
  __shared__ float elr_s[16*4];
  const int t = threadIdx.x;
  const int gq = t >> 4, c = t & 15;         // group(node), lane-in-group
  const int n0 = blockIdx.x*16;
  const int n = n0 + gq;
  const bool nv = n < N;
  if (t < 64) elr_s[t] = 0.f;

  // ---- agg phase ----
  int beg = 0, end = 0;
  float er0 = 0.f, er1 = 0.f;
  if (nv){
    beg = row_ptr[n]; end = row_ptr[n+1];
    er0 = elr[n*4+2]; er1 = elr[n*4+3];
  }
  const char* fhbB = (const char*)fhb;
  const unsigned cb = (unsigned)c << 4;

  float acc[8];
  #pragma unroll
  for (int k = 0; k < 8; k++) acc[k] = 0.f;
  float den0 = 0.f, den1 = 0.f;

  int i = beg;
  for (; i + 3 < end; i += 4){               // 4-deep: 4 independent chains
    int s0 = ssrc[i],   s1 = ssrc[i+1];
    int s2 = ssrc[i+2], s3 = ssrc[i+3];
    float2 el0 = *(const float2*)(elr + s0*4);
    float2 el1 = *(const float2*)(elr + s1*4);
    float2 el2 = *(const float2*)(elr + s2*4);
    float2 el3 = *(const float2*)(elr + s3*4);
    uint4 w0 = *(const uint4*)(fhbB + (((unsigned)s0 << 8) + cb));
    uint4 w1 = *(const uint4*)(fhbB + (((unsigned)s1 << 8) + cb));
    uint4 w2 = *(const uint4*)(fhbB + (((unsigned)s2 << 8) + cb));
    uint4 w3 = *(const uint4*)(fhbB + (((unsigned)s3 << 8) + cb));
    float e00 = __expf(fminf(lrelu(el0.x + er0), 30.f));
    float e10 = __expf(fminf(lrelu(el1.x + er0), 30.f));
    float e20 = __expf(fminf(lrelu(el2.x + er0), 30.f));
    float e30 = __expf(fminf(lrelu(el3.x + er0), 30.f));
    float e01 = __expf(fminf(lrelu(el0.y + er1), 30.f));
    float e11 = __expf(fminf(lrelu(el1.y + er1), 30.f));
    float e21 = __expf(fminf(lrelu(el2.y + er1), 30.f));
    float e31 = __expf(fminf(lrelu(el3.y + er1), 30.f));
    den0 += (e00 + e10) + (e20 + e30);
    den1 += (e01 + e11) + (e21 + e31);
    float a0 = (c < 8) ? e00 : e01;          // head = col/64
    float a1 = (c < 8) ? e10 : e11;
    float a2 = (c < 8) ? e20 : e21;
    float a3 = (c < 8) ? e30 : e31;
    const __half2* h0 = (const __half2*)&w0;
    const __half2* h1 = (const __half2*)&w1;
    const __half2* h2 = (const __half2*)&w2;
    const __half2* h3 = (const __half2*)&w3;
    #pragma unroll
    for (int q = 0; q < 4; q++){
      acc[2*q]   = fmaf((float)h0[q].x, a0, acc[2*q]);
      acc[2*q+1] = fmaf((float)h0[q].y, a0, acc[2*q+1]);
      acc[2*q]   = fmaf((float)h1[q].x, a1, acc[2*q]);
      acc[2*q+1] = fmaf((float)h1[q].y, a1, acc[2*q+1]);
      acc[2*q]   = fmaf((float)h2[q].x, a2, acc[2*q]);
      acc[2*q+1] = fmaf((float)h2[q].y, a2, acc[2*q+1]);
      acc[2*q]   = fmaf((float)h3[q].x, a3, acc[2*q]);
      acc[2*q+1] = fmaf((float)h3[q].y, a3, acc[2*q+1]);
    }
  }
  for (; i < end; i++){                      // tail: 0-3 edges
    int s0 = ssrc[i];
    float2 el0 = *(const float2*)(elr + s0*4);
    float e00 = __expf(fminf(lrelu(el0.x + er0), 30.f));
    float e01 = __expf(fminf(lrelu(el0.y + er1), 30.f));
    den0 += e00; den1 += e01;
    uint4 w0 = *(const uint4*)(fhbB + (((unsigned)s0 << 8) + cb));
    float a0 = (c < 8) ? e00 : e01;
    const __half2* h0 = (const __half2*)&w0;
    #pragma unroll
    for (int q = 0; q < 4; q++){
      acc[2*q]   = fmaf((float)h0[q].x, a0, acc[2*q]);
      acc[2*q+1] = fmaf((float)h0[q].y, a0, acc[2*q+1]);
    }
  }

  float rd0 = den0 > 0.f ? 1.f/den0 : 0.f;
  float rd1 = den1 > 0.f ? 1.f/den1 : 0.f;

  // epilogue: o = elu(acc/den + bias (+res)); pack f16 into LDS h tile
  uint4 hv = make_uint4(0,0,0,0);
  if (nv){
    float rs = (c < 8) ? rd0 : rd1;
    float o[8];
    const float4* b4 = (const float4*)(bias + c*8);
    float4 ba = b4[0], bb = b4[1];
    o[0]=fmaf(acc[0],rs,ba.x); o[1]=fmaf(acc[1],rs,ba.y);
    o[2]=fmaf(acc[2],rs,ba.z); o[3]=fmaf(acc[3],rs,ba.w);
    o[4]=fmaf(acc[4],rs,bb.x); o[5]=fmaf(acc[5],rs,bb.y);
    o[6]=fmaf(acc[6],rs,bb.z); o[7]=fmaf(acc[7],rs,bb.w);
    if (res){
      const float4* r4 = (const float4*)(res + (size_t)n*128 + c*8);
      float4 ra = r4[0], rb = r4[1];
      o[0]+=ra.x; o[1]+=ra.y; o[2]+=ra.z; o[3]+=ra.w;
      o[4]+=rb.x; o[5]+=rb.y; o[6]+=rb.z; o[7]+=rb.w;
    }
    #pragma unroll
    for (int k = 0; k < 8; k++) o[k] = elu1(o[k]);
    if (out){
      float4* o4 = (float4*)(out + (size_t)n*128 + c*8);
      o4[0] = make_float4(o[0], o[1], o[2], o[3]);
      o4[1] = make_float4(o[4], o[5], o[6], o[7]);
    }
    hv.x = (unsigned)f2h(o[0]) | ((unsigned)f2h(o[1]) << 16);
    hv.y = (unsigned)f2h(o[2]) | ((unsigned)f2h(o[3]) << 16);
    hv.z = (unsigned)f2h(o[4]) | ((unsigned)f2h(o[5]) << 16);
    hv.w = (unsigned)f2h(o[6]) | ((unsigned)f2h(o[7]) << 16);
  }
  *(uint4*)((char*)h_s + gq*272 + c*16) = hv;
  __syncthreads();

  // ---- gemm phase: 16 rows x 128 cols; wave wid owns cols wid*32..+31 ----
  const int lane = t & 63, wid = t >> 6;
  const int l15 = lane & 15, quad = lane >> 4;
  const int head = wid >> 1;                 // waves 0,1: head0; 2,3: head1

  half8 a[4];
  #pragma unroll
  for (int s = 0; s < 4; s++)
    a[s] = *(const half8*)((const char*)h_s + l15*272 + s*64 + quad*16);

  const int col0 = wid*32 + l15;
  const int col1 = col0 + 16;
  float4v ac0 = float4v{0.f,0.f,0.f,0.f}, ac1 = float4v{0.f,0.f,0.f,0.f};
  #pragma unroll
  for (int s = 0; s < 4; s++){
    half8 b0 = *(const half8*)(Wtn + (size_t)col0*128 + s*32 + quad*8);
    half8 b1 = *(const half8*)(Wtn + (size_t)col1*128 + s*32 + quad*8);
    ac0 = __builtin_amdgcn_mfma_f32_16x16x32_f16(a[s], b0, ac0, 0, 0, 0);
    ac1 = __builtin_amdgcn_mfma_f32_16x16x32_f16(a[s], b1, ac1, 0, 0, 0);
  }

  bool hv0 = (HN == 2) || (col0 < 64);
  bool hv1 = (HN == 2) || (col1 < 64);
  float al0 = hv0 ? aln[col0] : 0.f, ar0 = hv0 ? arn[col0] : 0.f;
  float al1 = hv1 ? aln[col1] : 0.f, ar1 = hv1 ? arn[col1] : 0.f;

  #pragma unroll
  for (int reg = 0; reg < 4; reg++){
    int nd = quad*4 + reg;                   // node within tile
    int row = n0 + nd;
    if (row < N){
      fhb_out[(size_t)row*128 + col0] = f2h(ac0[reg]);
      fhb_out[(size_t)row*128 + col1] = f2h(ac1[reg]);
    }
    float pel = ac0[reg]*al0 + ac1[reg]*al1;
    float per = ac0[reg]*ar0 + ac1[reg]*ar1;
    #pragma unroll
    for (int off = 1; off < 16; off <<= 1){
      pel += __shfl_xor(pel, off, 64);
      per += __shfl_xor(per, off, 64);
    }
    if (l15 == 0){
      atomicAdd(&elr_s[nd*4 + head], pel);
      atomicAdd(&elr_s[nd*4 + 2 + head], per);
    }
  }
  __syncthreads();
  if (t < 64){
    int nd = t >> 2, comp = t & 3;
    int row = n0 + nd;
    if (row < N) elr_out[row*4 + comp] = elr_s[t];
  }
}

// Final aggregation (layer 2, H=1): group-per-node, 4-deep, projected residual
// from fhb cols 64..127; writes float out. (R15 structure.)
__global__ __launch_bounds__(256) void k_agg_fin(
    const unsigned short* __restrict__ fhb,  // [N][128] f16
    const float* __restrict__ elr,           // [N][4]
    const int* __restrict__ row_ptr, const int* __restrict__ ssrc,
    const float* __restrict__ bias,
    float* __restrict__ out, int N){
  const int t = threadIdx.x;
  const int gq = t >> 4, c = t & 15;
  const int n = blockIdx.x*16 + gq;
  if (n >= N) return;
  const int beg = row_ptr[n], end = row_ptr[n+1];
  const float er0 = elr[n*4+2];

  const char* fhbB = (const char*)fhb;
  const unsigned cb = (unsigned)c << 3;      // 8B chunk, cols 0..63

  float acc[4];
  #pragma unroll
  for (int k = 0; k < 4; k++) acc[k] = 0.f;
  float den0 = 0.f;

  int i = beg;
  for (; i + 3 < end; i += 4){
    int s0 = ssrc[i],   s1 = ssrc[i+1];
    int s2 = ssrc[i+2], s3 = ssrc[i+3];
    float el0 = elr[s0*4], el1 = elr[s1*4];
    float el2 = elr[s2*4], el3 = elr[s3*4];
    uint2 w0 = *(const uint2*)(fhbB + (((unsigned)s0 << 8) + cb));
    uint2 w1 = *(const uint2*)(fhbB + (((unsigned)s1 << 8) + cb));
    uint2 w2 = *(const uint2*)(fhbB + (((unsigned)s2 << 8) + cb));
    uint2 w3 = *(const uint2*)(fhbB + (((unsigned)s3 << 8) + cb));
    float e00 = __expf(fminf(lrelu(el0 + er0), 30.f));
    float e10 = __expf(fminf(lrelu(el1 + er0), 30.f));
    float e20 = __expf(fminf(lrelu(el2 + er0), 30.f));
    float e30 = __expf(fminf(lrelu(el3 + er0), 30.f));
    den0 += (e00 + e10) + (e20 + e30);
    const __half2* h0 = (const __half2*)&w0;
    const __half2* h1 = (const __half2*)&w1;
    const __half2* h2 = (const __half2*)&w2;
    const __half2* h3 = (const __half2*)&w3;
    #pragma unroll
    for (int q = 0; q < 2; q++){
      acc[2*q]   = fmaf((float)h0[q].x, e00, acc[2*q]);
      acc[2*q+1] = fmaf((float)h0[q].y, e00, acc[2*q+1]);
      acc[2*q]   = fmaf((float)h1[q].x, e10, acc[2*q]);
      acc[2*q+1] = fmaf((float)h1[q].y, e10, acc[2*q+1]);
      acc[2*q]   = fmaf((float)h2[q].x, e20, acc[2*q]);
      acc[2*q+1] = fmaf((float)h2[q].y, e20, acc[2*q+1]);
      acc[2*q]   = fmaf((float)h3[q].x, e30, acc[2*q]);
      acc[2*q+1] = fmaf((float)h3[q].y, e30, acc[2*q+1]);
    }
  }
  for (; i < end; i++){
    int s0 = ssrc[i];
    float e00 = __expf(fminf(lrelu(elr[s0*4] + er0), 30.f));
    den0 += e00;
    uint2 w0 = *(const uint2*)(fhbB + (((unsigned)s0 << 8) + cb));
    const __half2* h0 = (const __half2*)&w0;
    #pragma unroll
    for (int q = 0; q < 2; q++){
      acc[2*q]   = fmaf((float)h0[q].x, e00, acc[2*q]);
      acc[2*q+1] = fmaf((float)h0[q].y, e00, acc[2*q+1]);
    }
  }

  float rd0 = den0 > 0.f ? 1.f/den0 : 0.f;
  float o[4];
  #pragma unroll
  for (int k = 0; k < 4; k++) o[k] = fmaf(acc[k], rd0, bias[c*4 + k]);
  // projected residual = row n cols 64..127; this lane's 4 cols at 128 + c*8
  uint2 r = *(const uint2*)(fhbB + (size_t)n*256 + 128 + c*8);
  const __half2* rp = (const __half2*)&r;
  o[0] += (float)rp[0].x; o[1] += (float)rp[0].y;
  o[2] += (float)rp[1].x; o[3] += (float)rp[1].y;
  *(float4*)(out + (size_t)n*64 + c*4) = make_float4(o[0], o[1], o[2], o[3]);
}

extern "C" void kernel_launch(void* const* d_in, const int* in_sizes, int n_in,
                              void* d_out, int out_size, void* d_ws, size_t ws_size,
                              hipStream_t stream) {
  const int*   feat = (const int*)  d_in[0];
  const float* fv   = (const float*)d_in[1];
  const int*   src  = (const int*)  d_in[2];
  const int*   dst  = (const int*)  d_in[3];
  const float* emb  = (const float*)d_in[4];
  const float* W0   = (const float*)d_in[5];
  const float* al0  = (const float*)d_in[6];
  const float* ar0  = (const float*)d_in[7];
  const float* b0   = (const float*)d_in[8];
  const float* W1   = (const float*)d_in[9];
  const float* al1  = (const float*)d_in[10];
  const float* ar1  = (const float*)d_in[11];
  const float* b1   = (const float*)d_in[12];
  const float* W2   = (const float*)d_in[13];
  const float* al2  = (const float*)d_in[14];
  const float* ar2  = (const float*)d_in[15];
  const float* b2   = (const float*)d_in[16];
  const float* rW2  = (const float*)d_in[17];
  const int N = in_sizes[0] / 8;   // 50000
  const int E = in_sizes[2];       // 800000

  size_t off = 0;
  auto alloc = [&](size_t bytes) -> void* {
    void* p = (char*)d_ws + off;
    off = (off + bytes + 255) & ~(size_t)255;
    return p;
  };
  unsigned short* FA = (unsigned short*)alloc((size_t)N*128*sizeof(unsigned short)); // fh ping
  unsigned short* FB = (unsigned short*)alloc((size_t)N*128*sizeof(unsigned short)); // fh pong
  float* EA     = (float*)alloc((size_t)N*4*sizeof(float));                          // elr ping
  float* EB     = (float*)alloc((size_t)N*4*sizeof(float));                          // elr pong
  float* P2     = (float*)alloc((size_t)N*128*sizeof(float));  // layer0 out (res for layer1)
  int* row_ptr  = (int*)alloc((size_t)(N+1)*sizeof(int));
  int* counts   = (int*)alloc((size_t)N*sizeof(int));
  int* rank     = (int*)alloc((size_t)E*sizeof(int));
  int* ssrc     = (int*)alloc((size_t)E*sizeof(int));
  int* bsum     = (int*)alloc(256*sizeof(int));
  unsigned short* Wt0 = (unsigned short*)alloc((size_t)128*64*sizeof(unsigned short));
  unsigned short* Wt1 = (unsigned short*)alloc((size_t)128*128*sizeof(unsigned short));
  unsigned short* Wt2 = (unsigned short*)alloc((size_t)128*128*sizeof(unsigned short));

  int nb1 = (N + 255) / 256;
  int eb  = (E + 255) / 256;
  int gt  = (N + 63)/64;
  int ngp = (N + 15)/16;

  // setup: zero counts + f16 weight preps (one launch)
  k_setup<<<(N + 128*64 + 2*128*128 + 255)/256, 256, 0, stream>>>(
      counts, N, W0, W1, W2, rW2, Wt0, Wt1, Wt2);
  // fused: layer-0 GEMM (EMBED) || edge histogram+rank
  k_gemm0_hist<<<gt + eb, 256, 0, stream>>>(feat, fv, emb, Wt0, al0, ar0,
                                            FA, EA, N, gt,
                                            dst, counts, rank, E);
  // CSR finish
  k_scan_local<<<nb1, 256, 0, stream>>>(counts, row_ptr, bsum, N);
  k_scan_top<<<1, 256, 0, stream>>>(bsum, nb1);
  k_scan_fix<<<nb1, 256, 0, stream>>>(row_ptr, bsum, N);
  k_scatter2<<<eb, 256, 0, stream>>>(src, dst, rank, row_ptr, ssrc, E);

  // layer 0 agg + layer 1 gemm (fused): reads FA/EA, writes P2 + FB/EB
  k_agg_gemm<2><<<ngp, 256, 0, stream>>>(FA, EA, row_ptr, ssrc, b0, nullptr,
                                         P2, Wt1, al1, ar1, FB, EB, N);
  // layer 1 agg + layer 2 gemm (fused): reads FB/EB (res=P2), writes FA/EA
  k_agg_gemm<1><<<ngp, 256, 0, stream>>>(FB, EB, row_ptr, ssrc, b1, P2,
                                         nullptr, Wt2, al2, ar2, FA, EA, N);
  // layer 2 final agg: reads FA/EA, projected residual from FA cols 64..127
  k_agg_fin<<<ngp, 256, 0, stream>>>(FA, EA, row_ptr, ssrc, b2,
                                     (float*)d_out, N);
}